// Round 8
// baseline (1579.675 us; speedup 1.0000x reference)
//
#include <hip/hip_runtime.h>
#include <hip/hip_bf16.h>

// Problem constants (fixed by setup_inputs)
#define Bn 16
#define Nn 4096
#define Pn 1024
#define Sn 32
#define Cn 64
#define EPSn 1e-5f
#define ALPHAn 0.2f

// Folded weights, OCTET-MAJOR [oct][K][8] -> wave-uniform s_load weight stream.
// K-orders permuted to match LDS row layouts:
//   W1: K=68 = [feat(64) | xyz(3) | zero-pad]
//   A : K=132 = [h3(128) | xyz(3) | zero-pad]
#define W1O 0       // [8][68][8]   = 4352
#define W2O 4352    // [8][64][8]   = 4096
#define W3O 8448    // [16][64][8]  = 8192
#define AO  16640   // [16][132][8] = 16896
#define B1O 33536   // 64
#define B2O 33600   // 64
#define B3O 33664   // 128
#define WSF 33792

__device__ __align__(16) float g_W[WSF];

__global__ void prep_kernel(
    const float* __restrict__ w1, const float* __restrict__ b1,
    const float* __restrict__ g1, const float* __restrict__ bt1,
    const float* __restrict__ m1, const float* __restrict__ v1,
    const float* __restrict__ w2, const float* __restrict__ b2,
    const float* __restrict__ g2, const float* __restrict__ bt2,
    const float* __restrict__ m2, const float* __restrict__ v2,
    const float* __restrict__ w3, const float* __restrict__ b3,
    const float* __restrict__ g3, const float* __restrict__ bt3,
    const float* __restrict__ m3, const float* __restrict__ v3,
    const float* __restrict__ a)
{
  const int idx = blockIdx.x * blockDim.x + threadIdx.x;
  if (idx >= WSF) return;
  float val;
  if (idx < W2O) {                         // W1: K-order [feat64|xyz3|pad]
    int r = idx; const int oct = r / 544; r -= oct * 544;
    const int k = r >> 3, o = oct * 8 + (r & 7);
    const float sc = g1[o] * rsqrtf(v1[o] + EPSn);
    val = (k < 64) ? w1[o * 67 + 3 + k] * sc
        : (k < 67) ? w1[o * 67 + (k - 64)] * sc : 0.f;
  } else if (idx < W3O) {                  // W2
    int r = idx - W2O; const int oct = r >> 9; r &= 511;
    const int k = r >> 3, o = oct * 8 + (r & 7);
    val = w2[o * 64 + k] * (g2[o] * rsqrtf(v2[o] + EPSn));
  } else if (idx < AO) {                   // W3
    int r = idx - W3O; const int oct = r >> 9; r &= 511;
    const int k = r >> 3, o = oct * 8 + (r & 7);
    val = w3[o * 64 + k] * (g3[o] * rsqrtf(v3[o] + EPSn));
  } else if (idx < B1O) {                  // A: K-order [h3(128)|xyz(3)|pad]
    int r = idx - AO; const int oct = r / 1056; r -= oct * 1056;
    const int k = r >> 3, o = oct * 8 + (r & 7);
    val = (k < 128) ? a[(3 + k) * 128 + o]
        : (k < 131) ? a[(k - 128) * 128 + o] : 0.f;
  } else if (idx < B2O) {
    const int o = idx - B1O;
    val = (b1[o] - m1[o]) * (g1[o] * rsqrtf(v1[o] + EPSn)) + bt1[o];
  } else if (idx < B3O) {
    const int o = idx - B2O;
    val = (b2[o] - m2[o]) * (g2[o] * rsqrtf(v2[o] + EPSn)) + bt2[o];
  } else {
    const int o = idx - B3O;
    val = (b3[o] - m3[o]) * (g3[o] * rsqrtf(v3[o] + EPSn)) + bt3[o];
  }
  g_W[idx] = val;
}

// LDS 52736 B == R4's PROVEN 3-blocks/CU size. Heavy lifetime aliasing:
//  A  [2*32*68]: input [feat64|rxyz3|pad]; h2 (cols0..63) ph2+; col67 rows0..2
//                holds new_xyz (zero-weight pad col); E64 aliases in ph5.
//  H3 [2*32*132]: h1 at cols4..71 (ph1-2); h3 cols0..127 (ph3+); rxyz 128..130;
//                 col131 zeroed (zero-weight pad).
//  F2 [128]: fps-feat (gather..ph1), then fps-h2 (ph2..ph3).
//  F3 [256]: F1=fps-h1 [g*64+o] (ph1..ph2); F3=fps-h3 [g*128+o] (ph3..ebias);
//            EB [g*128+o] (ebias..ph5).
#define OFF_A    0
#define OFF_E    0      // 2*32*65 = 4160 <= 4352, aliases dead A in phase 5
#define OFF_H3   4352
#define OFF_F2   12800
#define OFF_F3   12928
#define SHF      13184  // 52736 B

__global__ __launch_bounds__(256) void fused_kernel(
    const float* __restrict__ xyz, const float* __restrict__ points,
    const int* __restrict__ fps_idx, const int* __restrict__ group_idx,
    float* __restrict__ out)
{
  __shared__ __align__(16) float SH[SHF];

  const int t    = threadIdx.x;
  const int lane = t & 63;
  const int grp  = lane >> 5;
  const int s    = lane & 31;
  const int wave = __builtin_amdgcn_readfirstlane(t >> 6);
  const int tg = t >> 7, tq = t & 127;
  const int gg = blockIdx.x * 2 + tg;
  const int b_t = gg >> 10, p_t = gg & 1023;

  // ---- fps point load (+ write out0 immediately: pure copy) ----
  {
    const int fi = fps_idx[gg];
    if (tq < 64) {
      SH[OFF_F2 + tg * 64 + tq] = points[b_t * Cn * Nn + tq * Nn + fi];
    } else if (tq < 67) {
      const int d = tq - 64;
      const float v = xyz[b_t * 3 * Nn + d * Nn + fi];
      SH[OFF_A + tg * 2176 + d * 68 + 67] = v;   // new_xyz in pad col
      out[(b_t * 3 + d) * Pn + p_t] = v;
    }
  }
  __syncthreads();

  // ---- gather neighbors: 128 thr/grp = 32 rows x 4 ch-quarters ----
  {
    const int s0 = tq >> 2, cg = tq & 3;
    const int gi = group_idx[gg * Sn + s0];
    const float* prow = points + b_t * Cn * Nn + gi;
    float* arow = SH + OFF_A + tg * 2176 + s0 * 68;
    const int c0 = cg * 16;
    #pragma unroll
    for (int k = 0; k < 16; ++k) arow[c0 + k] = prow[(c0 + k) * Nn];
    if (cg == 0) {
      float* hrow = SH + OFF_H3 + tg * 4224 + s0 * 132;
      #pragma unroll
      for (int d = 0; d < 3; ++d) {
        const float r = xyz[b_t * 3 * Nn + d * Nn + gi]
                      - SH[OFF_A + tg * 2176 + d * 68 + 67];
        arow[64 + d] = r;
        hrow[128 + d] = r;
      }
      hrow[131] = 0.f;                  // zero-weight pad, must be finite
      if (s0 >= 3) arow[67] = 0.f;      // rows 0..2 hold new_xyz (finite)
    }
  }
  __syncthreads();

  const float* inA = SH + OFF_A + grp * 2176 + s * 68;

  // ===== Phase 1: 67->64 (K=68). h1 -> H3 cols 4..67 =====
  #pragma unroll
  for (int pass = 0; pass < 2; ++pass) {
    const int oct = wave + 4 * pass;
    const int wof = __builtin_amdgcn_readfirstlane(W1O + oct * 544);
    const int bof = __builtin_amdgcn_readfirstlane(B1O + oct * 8);
    float acc[8];
    #pragma unroll
    for (int j = 0; j < 8; ++j) acc[j] = g_W[bof + j];
    #pragma unroll 4
    for (int i4 = 0; i4 < 68; i4 += 4) {
      const float4 v4 = *(const float4*)(inA + i4);
      const float* wp = g_W + wof + i4 * 8;
      #pragma unroll
      for (int j = 0; j < 8; ++j) acc[j] = fmaf(v4.x, wp[j], acc[j]);
      #pragma unroll
      for (int j = 0; j < 8; ++j) acc[j] = fmaf(v4.y, wp[8 + j], acc[j]);
      #pragma unroll
      for (int j = 0; j < 8; ++j) acc[j] = fmaf(v4.z, wp[16 + j], acc[j]);
      #pragma unroll
      for (int j = 0; j < 8; ++j) acc[j] = fmaf(v4.w, wp[24 + j], acc[j]);
    }
    float* o1 = SH + OFF_H3 + grp * 4224 + s * 132 + 4 + oct * 8;
    float4 r0, r1;
    r0.x = fmaxf(acc[0], 0.f); r0.y = fmaxf(acc[1], 0.f);
    r0.z = fmaxf(acc[2], 0.f); r0.w = fmaxf(acc[3], 0.f);
    r1.x = fmaxf(acc[4], 0.f); r1.y = fmaxf(acc[5], 0.f);
    r1.z = fmaxf(acc[6], 0.f); r1.w = fmaxf(acc[7], 0.f);
    *(float4*)o1 = r0; *(float4*)(o1 + 4) = r1;
  }
  // fps layer1: o=tq>>1, K split [0,34) / [34,67)
  {
    const int o = tq >> 1, kh = tq & 1;
    const float* wp = g_W + W1O + (o >> 3) * 544 + (o & 7);
    float a = 0.f;
    if (kh == 0) {
      #pragma unroll 2
      for (int i = 0; i < 34; ++i)
        a = fmaf(SH[OFF_F2 + tg * 64 + i], wp[i * 8], a);
    } else {
      #pragma unroll 2
      for (int i = 34; i < 64; ++i)
        a = fmaf(SH[OFF_F2 + tg * 64 + i], wp[i * 8], a);
      #pragma unroll
      for (int d = 0; d < 3; ++d)
        a = fmaf(SH[OFF_A + tg * 2176 + d * 68 + 67], wp[(64 + d) * 8], a);
    }
    a += __shfl_xor(a, 1);
    if (kh == 0)
      SH[OFF_F3 + tg * 64 + o] = fmaxf(a + g_W[B1O + o], 0.f);  // F1
  }
  __syncthreads();

  // ===== Phase 2: 64->64. Reads h1 (H3 cols 4..67), writes h2 -> A cols 0..63 =====
  {
    const float* inH1 = SH + OFF_H3 + grp * 4224 + s * 132 + 4;
    #pragma unroll
    for (int pass = 0; pass < 2; ++pass) {
      const int oct = wave + 4 * pass;
      const int wof = __builtin_amdgcn_readfirstlane(W2O + oct * 512);
      const int bof = __builtin_amdgcn_readfirstlane(B2O + oct * 8);
      float acc[8];
      #pragma unroll
      for (int j = 0; j < 8; ++j) acc[j] = g_W[bof + j];
      #pragma unroll 4
      for (int i4 = 0; i4 < 64; i4 += 4) {
        const float4 v4 = *(const float4*)(inH1 + i4);
        const float* wp = g_W + wof + i4 * 8;
        #pragma unroll
        for (int j = 0; j < 8; ++j) acc[j] = fmaf(v4.x, wp[j], acc[j]);
        #pragma unroll
        for (int j = 0; j < 8; ++j) acc[j] = fmaf(v4.y, wp[8 + j], acc[j]);
        #pragma unroll
        for (int j = 0; j < 8; ++j) acc[j] = fmaf(v4.z, wp[16 + j], acc[j]);
        #pragma unroll
        for (int j = 0; j < 8; ++j) acc[j] = fmaf(v4.w, wp[24 + j], acc[j]);
      }
      float* o2 = SH + OFF_A + grp * 2176 + s * 68 + oct * 8;
      float4 r0, r1;
      r0.x = fmaxf(acc[0], 0.f); r0.y = fmaxf(acc[1], 0.f);
      r0.z = fmaxf(acc[2], 0.f); r0.w = fmaxf(acc[3], 0.f);
      r1.x = fmaxf(acc[4], 0.f); r1.y = fmaxf(acc[5], 0.f);
      r1.z = fmaxf(acc[6], 0.f); r1.w = fmaxf(acc[7], 0.f);
      *(float4*)o2 = r0; *(float4*)(o2 + 4) = r1;
    }
  }
  // fps layer2: reads F1, writes F2 (over dead fps-feat)
  {
    const int o = tq >> 1, kh = tq & 1;
    const float* wp = g_W + W2O + (o >> 3) * 512 + (o & 7);
    float a = 0.f;
    #pragma unroll 2
    for (int i = kh * 32; i < kh * 32 + 32; ++i)
      a = fmaf(SH[OFF_F3 + tg * 64 + i], wp[i * 8], a);
    a += __shfl_xor(a, 1);
    if (kh == 0)
      SH[OFF_F2 + tg * 64 + o] = fmaxf(a + g_W[B2O + o], 0.f);
  }
  __syncthreads();

  // ===== Phase 3: 64->128. Reads h2 (A), writes h3 -> H3 cols 0..127 =====
  #pragma unroll
  for (int pass = 0; pass < 4; ++pass) {
    const int oct = wave + 4 * pass;
    const int wof = __builtin_amdgcn_readfirstlane(W3O + oct * 512);
    const int bof = __builtin_amdgcn_readfirstlane(B3O + oct * 8);
    float acc[8];
    #pragma unroll
    for (int j = 0; j < 8; ++j) acc[j] = g_W[bof + j];
    #pragma unroll 4
    for (int i4 = 0; i4 < 64; i4 += 4) {
      const float4 v4 = *(const float4*)(inA + i4);   // h2
      const float* wp = g_W + wof + i4 * 8;
      #pragma unroll
      for (int j = 0; j < 8; ++j) acc[j] = fmaf(v4.x, wp[j], acc[j]);
      #pragma unroll
      for (int j = 0; j < 8; ++j) acc[j] = fmaf(v4.y, wp[8 + j], acc[j]);
      #pragma unroll
      for (int j = 0; j < 8; ++j) acc[j] = fmaf(v4.z, wp[16 + j], acc[j]);
      #pragma unroll
      for (int j = 0; j < 8; ++j) acc[j] = fmaf(v4.w, wp[24 + j], acc[j]);
    }
    float* o3 = SH + OFF_H3 + grp * 4224 + s * 132 + oct * 8;
    float4 r0, r1;
    r0.x = fmaxf(acc[0], 0.f); r0.y = fmaxf(acc[1], 0.f);
    r0.z = fmaxf(acc[2], 0.f); r0.w = fmaxf(acc[3], 0.f);
    r1.x = fmaxf(acc[4], 0.f); r1.y = fmaxf(acc[5], 0.f);
    r1.z = fmaxf(acc[6], 0.f); r1.w = fmaxf(acc[7], 0.f);
    *(float4*)o3 = r0; *(float4*)(o3 + 4) = r1;
  }
  // fps layer3: reads F2, writes F3 [g*128+o] (over dead F1)
  {
    const int o = tq;
    const float* wp = g_W + W3O + (o >> 3) * 512 + (o & 7);
    float a = 0.f;
    #pragma unroll 4
    for (int i = 0; i < 64; ++i)
      a = fmaf(SH[OFF_F2 + tg * 64 + i], wp[i * 8], a);
    SH[OFF_F3 + tg * 128 + o] = fmaxf(a + g_W[B3O + o], 0.f);
  }
  __syncthreads();

  // ===== ebias: EB[g][o] = [F3|new_xyz] . a_col(o); EB overwrites F3 =====
  {
    const int q = lane & 31;
    const int eoct = wave + 4 * (q >> 3);   // waves x (q>>3) cover all 16 octets
    const int ej = q & 7;
    const float* ap = g_W + AO + eoct * 1056 + ej;
    const float* f3 = SH + OFF_F3 + grp * 128;
    float a = 0.f;
    #pragma unroll 4
    for (int k = 0; k < 128; ++k) a = fmaf(f3[k], ap[k * 8], a);
    #pragma unroll
    for (int d = 0; d < 3; ++d)
      a = fmaf(SH[OFF_A + grp * 2176 + d * 68 + 67], ap[(128 + d) * 8], a);
    __syncthreads();                        // all F3 reads done
    SH[OFF_F3 + grp * 128 + eoct * 8 + ej] = a;   // EB
  }
  __syncthreads();

  // ===== Phase 5 + softmax, split in column halves (E64 aliases dead A) =====
  const float* inH = SH + OFF_H3 + grp * 4224 + s * 132;
  #pragma unroll
  for (int half = 0; half < 2; ++half) {
    #pragma unroll
    for (int pp = 0; pp < 2; ++pp) {
      const int oct = wave + 4 * (half * 2 + pp);   // half0: 0..7, half1: 8..15
      const int wof = __builtin_amdgcn_readfirstlane(AO + oct * 1056);
      float acc[8];
      #pragma unroll
      for (int j = 0; j < 8; ++j) acc[j] = 0.f;
      #pragma unroll 4
      for (int i4 = 0; i4 < 132; i4 += 4) {
        const float4 v4 = *(const float4*)(inH + i4);  // [h3|rxyz|0]
        const float* wp = g_W + wof + i4 * 8;
        #pragma unroll
        for (int j = 0; j < 8; ++j) acc[j] = fmaf(v4.x, wp[j], acc[j]);
        #pragma unroll
        for (int j = 0; j < 8; ++j) acc[j] = fmaf(v4.y, wp[8 + j], acc[j]);
        #pragma unroll
        for (int j = 0; j < 8; ++j) acc[j] = fmaf(v4.z, wp[16 + j], acc[j]);
        #pragma unroll
        for (int j = 0; j < 8; ++j) acc[j] = fmaf(v4.w, wp[24 + j], acc[j]);
      }
      const float* ebp = SH + OFF_F3 + grp * 128 + oct * 8;
      float* erow = SH + OFF_E + grp * 2080 + s * 65 + (oct & 7) * 8;
      #pragma unroll
      for (int j = 0; j < 8; ++j) {
        const float e = ebp[j] - acc[j];
        erow[j] = (e > 0.f) ? e : ALPHAn * e;
      }
    }
    __syncthreads();
    // column softmax over s for cols half*64 + (0..63); threads 128..255 dup
    {
      const int c = tq & 63, g2 = tq >> 6;
      const float* ecol = SH + OFF_E + g2 * 2080 + c;
      const float* hcol = SH + OFF_H3 + g2 * 4224 + half * 64 + c;
      float mx = -3.4e38f;
      #pragma unroll 4
      for (int si = 0; si < 32; ++si) mx = fmaxf(mx, ecol[si * 65]);
      float den = 0.f, pool = 0.f;
      #pragma unroll 4
      for (int si = 0; si < 32; ++si) {
        const float w = __expf(ecol[si * 65] - mx);
        den += w;
        pool = fmaf(w, hcol[si * 132], pool);
      }
      const int gg2 = blockIdx.x * 2 + g2;
      out[Bn * 3 * Pn + (((gg2 >> 10) * 128) + half * 64 + c) * Pn + (gg2 & 1023)]
          = pool / den;
    }
    __syncthreads();   // protect E64 reuse by next half
  }
}

extern "C" void kernel_launch(void* const* d_in, const int* in_sizes, int n_in,
                              void* d_out, int out_size, void* d_ws, size_t ws_size,
                              hipStream_t stream) {
  const float* xyz       = (const float*)d_in[0];
  const float* points    = (const float*)d_in[1];
  const int*   fps_idx   = (const int*)d_in[2];
  const int*   group_idx = (const int*)d_in[3];

  prep_kernel<<<(WSF + 255) / 256, 256, 0, stream>>>(
      (const float*)d_in[4],  (const float*)d_in[5],
      (const float*)d_in[6],  (const float*)d_in[7],
      (const float*)d_in[8],  (const float*)d_in[9],
      (const float*)d_in[10], (const float*)d_in[11],
      (const float*)d_in[12], (const float*)d_in[13],
      (const float*)d_in[14], (const float*)d_in[15],
      (const float*)d_in[16], (const float*)d_in[17],
      (const float*)d_in[18], (const float*)d_in[19],
      (const float*)d_in[20], (const float*)d_in[21],
      (const float*)d_in[22]);

  fused_kernel<<<Bn * Pn / 2, 256, 0, stream>>>(xyz, points, fps_idx, group_idx,
                                                (float*)d_out);
}

// Round 9
// 826.982 us; speedup vs baseline: 1.9102x; 1.9102x over previous
//
#include <hip/hip_runtime.h>
#include <hip/hip_bf16.h>

#define Bn 16
#define Nn 4096
#define Pn 1024
#define Sn 32
#define Cn 64
#define EPSn 1e-5f
#define ALPHAn 0.2f

// Folded weights [K][N] row-major; K padded/ordered to match LDS act rows.
//   W1 [68][64]  K=[feat64|xyz3|zeropad]
//   W2 [64][64]
//   W3 [64][128]
//   A  two col-halves [132][64] each; K=[h3(128)|xyz3|zeropad]
#define W1O 0
#define W2O 4352
#define W3O 8448
#define AO  16640
#define B1O 33536
#define B2O 33600
#define B3O 33664
#define WSF 33792

__device__ __align__(16) float g_W[WSF];

__global__ void prep_kernel(
    const float* __restrict__ w1, const float* __restrict__ b1,
    const float* __restrict__ g1, const float* __restrict__ bt1,
    const float* __restrict__ m1, const float* __restrict__ v1,
    const float* __restrict__ w2, const float* __restrict__ b2,
    const float* __restrict__ g2, const float* __restrict__ bt2,
    const float* __restrict__ m2, const float* __restrict__ v2,
    const float* __restrict__ w3, const float* __restrict__ b3,
    const float* __restrict__ g3, const float* __restrict__ bt3,
    const float* __restrict__ m3, const float* __restrict__ v3,
    const float* __restrict__ a)
{
  const int idx = blockIdx.x * blockDim.x + threadIdx.x;
  if (idx >= WSF) return;
  float val;
  if (idx < W2O) {                       // W1 [68][64]
    const int k = idx >> 6, o = idx & 63;
    const float sc = g1[o] * rsqrtf(v1[o] + EPSn);
    val = (k < 64) ? w1[o * 67 + 3 + k] * sc
        : (k < 67) ? w1[o * 67 + (k - 64)] * sc : 0.f;
  } else if (idx < W3O) {                // W2 [64][64]
    const int r = idx - W2O, k = r >> 6, o = r & 63;
    val = w2[o * 64 + k] * (g2[o] * rsqrtf(v2[o] + EPSn));
  } else if (idx < AO) {                 // W3 [64][128]
    const int r = idx - W3O, k = r >> 7, o = r & 127;
    val = w3[o * 64 + k] * (g3[o] * rsqrtf(v3[o] + EPSn));
  } else if (idx < B1O) {                // A halves [132][64] x2
    int r = idx - AO;
    const int half = r / 8448; r -= half * 8448;
    const int k = r >> 6, o = half * 64 + (r & 63);
    val = (k < 128) ? a[(3 + k) * 128 + o]
        : (k < 131) ? a[(k - 128) * 128 + o] : 0.f;
  } else if (idx < B2O) {
    const int o = idx - B1O;
    val = (b1[o] - m1[o]) * (g1[o] * rsqrtf(v1[o] + EPSn)) + bt1[o];
  } else if (idx < B3O) {
    const int o = idx - B2O;
    val = (b2[o] - m2[o]) * (g2[o] * rsqrtf(v2[o] + EPSn)) + bt2[o];
  } else {
    const int o = idx - B3O;
    val = (b3[o] - m3[o]) * (g3[o] * rsqrtf(v3[o] + EPSn)) + bt3[o];
  }
  g_W[idx] = val;
}

// LDS (floats), 2 groups/block. 69120 B -> 2 blocks/CU.
//  AIN [2][32][68]: [feat64|rxyz3|pad(new_xyz rows0-2 / 0)]; h2 cols0..63 (ph2+);
//                   E scores alias here in ph5 (stride 68, cols0..63).
//  H3  [2][32][132]: h1 cols0..63 (ph1-2); h3 cols0..127 (ph3+); rxyz 128..130; 0 @131.
//  F2  [2][64]: fps feat -> fps h2.   F3 [2][128]: F1 -> F3 -> EB.
#define L_AIN 0
#define L_H3  4352
#define L_WB0 12800
#define L_WB1 14848
#define L_F2  16896
#define L_F3  17024
#define SHF   17280

__device__ __forceinline__ void stage_async(const float* src, float* dst,
                                            int count, int t) {
  #pragma unroll
  for (int j = 0; j < count; j += 1024) {
    if (4 * t < count - j) {
      __builtin_amdgcn_global_load_lds(
          (const __attribute__((address_space(1))) void*)(src + j + 4 * t),
          (__attribute__((address_space(3))) void*)(dst + j + 4 * t),
          16, 0, 0);
    }
  }
}

__device__ __forceinline__ void fma8x2(const float* __restrict__ wp,
                                       float a0, float a1,
                                       float* __restrict__ A0,
                                       float* __restrict__ A1) {
  const float4 w0 = *(const float4*)(wp);
  const float4 w1 = *(const float4*)(wp + 4);
  A0[0]=fmaf(a0,w0.x,A0[0]); A0[1]=fmaf(a0,w0.y,A0[1]);
  A0[2]=fmaf(a0,w0.z,A0[2]); A0[3]=fmaf(a0,w0.w,A0[3]);
  A0[4]=fmaf(a0,w1.x,A0[4]); A0[5]=fmaf(a0,w1.y,A0[5]);
  A0[6]=fmaf(a0,w1.z,A0[6]); A0[7]=fmaf(a0,w1.w,A0[7]);
  A1[0]=fmaf(a1,w0.x,A1[0]); A1[1]=fmaf(a1,w0.y,A1[1]);
  A1[2]=fmaf(a1,w0.z,A1[2]); A1[3]=fmaf(a1,w0.w,A1[3]);
  A1[4]=fmaf(a1,w1.x,A1[4]); A1[5]=fmaf(a1,w1.y,A1[5]);
  A1[6]=fmaf(a1,w1.z,A1[6]); A1[7]=fmaf(a1,w1.w,A1[7]);
}

__device__ __forceinline__ void fma16x2(const float* __restrict__ wp,
                                        float a0, float a1,
                                        float* __restrict__ A0,
                                        float* __restrict__ A1) {
  const float4 w0 = *(const float4*)(wp);
  const float4 w1 = *(const float4*)(wp + 4);
  const float4 w2 = *(const float4*)(wp + 64);
  const float4 w3 = *(const float4*)(wp + 68);
  A0[0]=fmaf(a0,w0.x,A0[0]);  A0[1]=fmaf(a0,w0.y,A0[1]);
  A0[2]=fmaf(a0,w0.z,A0[2]);  A0[3]=fmaf(a0,w0.w,A0[3]);
  A0[4]=fmaf(a0,w1.x,A0[4]);  A0[5]=fmaf(a0,w1.y,A0[5]);
  A0[6]=fmaf(a0,w1.z,A0[6]);  A0[7]=fmaf(a0,w1.w,A0[7]);
  A0[8]=fmaf(a0,w2.x,A0[8]);  A0[9]=fmaf(a0,w2.y,A0[9]);
  A0[10]=fmaf(a0,w2.z,A0[10]); A0[11]=fmaf(a0,w2.w,A0[11]);
  A0[12]=fmaf(a0,w3.x,A0[12]); A0[13]=fmaf(a0,w3.y,A0[13]);
  A0[14]=fmaf(a0,w3.z,A0[14]); A0[15]=fmaf(a0,w3.w,A0[15]);
  A1[0]=fmaf(a1,w0.x,A1[0]);  A1[1]=fmaf(a1,w0.y,A1[1]);
  A1[2]=fmaf(a1,w0.z,A1[2]);  A1[3]=fmaf(a1,w0.w,A1[3]);
  A1[4]=fmaf(a1,w1.x,A1[4]);  A1[5]=fmaf(a1,w1.y,A1[5]);
  A1[6]=fmaf(a1,w1.z,A1[6]);  A1[7]=fmaf(a1,w1.w,A1[7]);
  A1[8]=fmaf(a1,w2.x,A1[8]);  A1[9]=fmaf(a1,w2.y,A1[9]);
  A1[10]=fmaf(a1,w2.z,A1[10]); A1[11]=fmaf(a1,w2.w,A1[11]);
  A1[12]=fmaf(a1,w3.x,A1[12]); A1[13]=fmaf(a1,w3.y,A1[13]);
  A1[14]=fmaf(a1,w3.z,A1[14]); A1[15]=fmaf(a1,w3.w,A1[15]);
}

__global__ __launch_bounds__(256) void fused_kernel(
    const float* __restrict__ xyz, const float* __restrict__ points,
    const int* __restrict__ fps_idx, const int* __restrict__ group_idx,
    float* __restrict__ out)
{
  __shared__ __align__(16) float SH[SHF];
  float* wb0 = SH + L_WB0;
  float* wb1 = SH + L_WB1;

  const int t  = threadIdx.x;
  const int s  = t & 31;
  const int o8 = (t >> 5) * 8;           // output octet cols
  const int tg = t >> 7, tq = t & 127;   // 2 groups x 128 threads
  const int gg = blockIdx.x * 2 + tg;
  const int b_t = gg >> 10, p_t = gg & 1023;

  float acc0[16], acc1[16];
  const float* aA0 = SH + L_AIN + s * 68;
  const float* aA1 = SH + L_AIN + 2176 + s * 68;
  const float* aH0 = SH + L_H3 + s * 132;
  const float* aH1 = SH + L_H3 + 4224 + s * 132;

  // ---- S0: issue c0 (W1 k0-31); fps point; out0 ----
  stage_async(g_W + W1O, wb0, 2048, t);
  {
    const int fi = fps_idx[gg];
    if (tq < 64) {
      SH[L_F2 + tg * 64 + tq] = points[b_t * Cn * Nn + tq * Nn + fi];
    } else if (tq < 67) {
      const int d = tq - 64;
      const float v = xyz[b_t * 3 * Nn + d * Nn + fi];
      SH[L_AIN + tg * 2176 + d * 68 + 67] = v;   // new_xyz in pad col rows0-2
      out[(b_t * 3 + d) * Pn + p_t] = v;
    }
  }
  __syncthreads();

  // ---- S1: issue c1 (W1 k32-63); gather neighbors ----
  stage_async(g_W + W1O + 2048, wb1, 2048, t);
  {
    const int s0 = tq >> 2, cg = tq & 3;
    const int gi = group_idx[gg * Sn + s0];
    const float* prow = points + b_t * Cn * Nn + gi;
    float* arow = SH + L_AIN + tg * 2176 + s0 * 68;
    const int c0 = cg * 16;
    #pragma unroll
    for (int k = 0; k < 16; ++k) arow[c0 + k] = prow[(c0 + k) * Nn];
    if (cg == 0) {
      float* hrow = SH + L_H3 + tg * 4224 + s0 * 132;
      #pragma unroll
      for (int d = 0; d < 3; ++d) {
        const float r = xyz[b_t * 3 * Nn + d * Nn + gi]
                      - SH[L_AIN + tg * 2176 + d * 68 + 67];
        arow[64 + d] = r;
        hrow[128 + d] = r;
      }
      hrow[131] = 0.f;
      if (s0 >= 3) arow[67] = 0.f;   // pad col finite (rows0-2 = new_xyz)
    }
  }
  __syncthreads();   // c0,c1 landed; gather visible

  // ===== Phase 1: 67->64 =====
  {
    const float4 bA = *(const float4*)(g_W + B1O + o8);
    const float4 bB = *(const float4*)(g_W + B1O + o8 + 4);
    acc0[0]=bA.x; acc0[1]=bA.y; acc0[2]=bA.z; acc0[3]=bA.w;
    acc0[4]=bB.x; acc0[5]=bB.y; acc0[6]=bB.z; acc0[7]=bB.w;
    #pragma unroll
    for (int j = 0; j < 8; ++j) acc1[j] = acc0[j];
  }
  // S2: compute c0 (k0-31)
  #pragma unroll 2
  for (int i4 = 0; i4 < 32; i4 += 4) {
    const float4 v0 = *(const float4*)(aA0 + i4);
    const float4 v1 = *(const float4*)(aA1 + i4);
    fma8x2(wb0 + (i4+0)*64 + o8, v0.x, v1.x, acc0, acc1);
    fma8x2(wb0 + (i4+1)*64 + o8, v0.y, v1.y, acc0, acc1);
    fma8x2(wb0 + (i4+2)*64 + o8, v0.z, v1.z, acc0, acc1);
    fma8x2(wb0 + (i4+3)*64 + o8, v0.w, v1.w, acc0, acc1);
  }
  __syncthreads();
  // S3: issue c2 (W1 k64-67); compute c1 (k32-63)
  stage_async(g_W + W1O + 4096, wb0, 256, t);
  #pragma unroll 2
  for (int i4 = 0; i4 < 32; i4 += 4) {
    const float4 v0 = *(const float4*)(aA0 + 32 + i4);
    const float4 v1 = *(const float4*)(aA1 + 32 + i4);
    fma8x2(wb1 + (i4+0)*64 + o8, v0.x, v1.x, acc0, acc1);
    fma8x2(wb1 + (i4+1)*64 + o8, v0.y, v1.y, acc0, acc1);
    fma8x2(wb1 + (i4+2)*64 + o8, v0.z, v1.z, acc0, acc1);
    fma8x2(wb1 + (i4+3)*64 + o8, v0.w, v1.w, acc0, acc1);
  }
  __syncthreads();
  // S4: issue c3 (W2 k0-31); compute c2 (k64-67); write h1; fps-L1
  stage_async(g_W + W2O, wb1, 2048, t);
  {
    const float4 v0 = *(const float4*)(aA0 + 64);
    const float4 v1 = *(const float4*)(aA1 + 64);
    fma8x2(wb0 + 0*64 + o8, v0.x, v1.x, acc0, acc1);
    fma8x2(wb0 + 1*64 + o8, v0.y, v1.y, acc0, acc1);
    fma8x2(wb0 + 2*64 + o8, v0.z, v1.z, acc0, acc1);
    fma8x2(wb0 + 3*64 + o8, v0.w, v1.w, acc0, acc1);
  }
  {
    float* h0 = SH + L_H3 + s * 132 + o8;
    float* h1p = SH + L_H3 + 4224 + s * 132 + o8;
    float4 r;
    r.x=fmaxf(acc0[0],0.f); r.y=fmaxf(acc0[1],0.f); r.z=fmaxf(acc0[2],0.f); r.w=fmaxf(acc0[3],0.f);
    *(float4*)h0 = r;
    r.x=fmaxf(acc0[4],0.f); r.y=fmaxf(acc0[5],0.f); r.z=fmaxf(acc0[6],0.f); r.w=fmaxf(acc0[7],0.f);
    *(float4*)(h0+4) = r;
    r.x=fmaxf(acc1[0],0.f); r.y=fmaxf(acc1[1],0.f); r.z=fmaxf(acc1[2],0.f); r.w=fmaxf(acc1[3],0.f);
    *(float4*)h1p = r;
    r.x=fmaxf(acc1[4],0.f); r.y=fmaxf(acc1[5],0.f); r.z=fmaxf(acc1[6],0.f); r.w=fmaxf(acc1[7],0.f);
    *(float4*)(h1p+4) = r;
  }
  {  // fps layer1
    const int o = tq >> 1, kh = tq & 1;
    float a = 0.f;
    if (kh == 0) {
      for (int k = 0; k < 34; ++k)
        a = fmaf(SH[L_F2 + tg * 64 + k], g_W[W1O + k * 64 + o], a);
    } else {
      for (int k = 34; k < 64; ++k)
        a = fmaf(SH[L_F2 + tg * 64 + k], g_W[W1O + k * 64 + o], a);
      #pragma unroll
      for (int d = 0; d < 3; ++d)
        a = fmaf(SH[L_AIN + tg * 2176 + d * 68 + 67], g_W[W1O + (64 + d) * 64 + o], a);
    }
    a += __shfl_xor(a, 1);
    if (kh == 0) SH[L_F3 + tg * 128 + o] = fmaxf(a + g_W[B1O + o], 0.f);  // F1
  }
  __syncthreads();

  // ===== Phase 2: 64->64 (acts h1 in H3 cols0-63) =====
  {
    const float4 bA = *(const float4*)(g_W + B2O + o8);
    const float4 bB = *(const float4*)(g_W + B2O + o8 + 4);
    acc0[0]=bA.x; acc0[1]=bA.y; acc0[2]=bA.z; acc0[3]=bA.w;
    acc0[4]=bB.x; acc0[5]=bB.y; acc0[6]=bB.z; acc0[7]=bB.w;
    #pragma unroll
    for (int j = 0; j < 8; ++j) acc1[j] = acc0[j];
  }
  // S5: issue c4 (W2 k32-63); compute c3
  stage_async(g_W + W2O + 2048, wb0, 2048, t);
  #pragma unroll 2
  for (int i4 = 0; i4 < 32; i4 += 4) {
    const float4 v0 = *(const float4*)(aH0 + i4);
    const float4 v1 = *(const float4*)(aH1 + i4);
    fma8x2(wb1 + (i4+0)*64 + o8, v0.x, v1.x, acc0, acc1);
    fma8x2(wb1 + (i4+1)*64 + o8, v0.y, v1.y, acc0, acc1);
    fma8x2(wb1 + (i4+2)*64 + o8, v0.z, v1.z, acc0, acc1);
    fma8x2(wb1 + (i4+3)*64 + o8, v0.w, v1.w, acc0, acc1);
  }
  __syncthreads();
  // S6: issue c5 (W3 k0-15); compute c4; write h2; fps-L2
  stage_async(g_W + W3O, wb1, 2048, t);
  #pragma unroll 2
  for (int i4 = 0; i4 < 32; i4 += 4) {
    const float4 v0 = *(const float4*)(aH0 + 32 + i4);
    const float4 v1 = *(const float4*)(aH1 + 32 + i4);
    fma8x2(wb0 + (i4+0)*64 + o8, v0.x, v1.x, acc0, acc1);
    fma8x2(wb0 + (i4+1)*64 + o8, v0.y, v1.y, acc0, acc1);
    fma8x2(wb0 + (i4+2)*64 + o8, v0.z, v1.z, acc0, acc1);
    fma8x2(wb0 + (i4+3)*64 + o8, v0.w, v1.w, acc0, acc1);
  }
  {
    float* h0 = SH + L_AIN + s * 68 + o8;
    float* h1p = SH + L_AIN + 2176 + s * 68 + o8;
    float4 r;
    r.x=fmaxf(acc0[0],0.f); r.y=fmaxf(acc0[1],0.f); r.z=fmaxf(acc0[2],0.f); r.w=fmaxf(acc0[3],0.f);
    *(float4*)h0 = r;
    r.x=fmaxf(acc0[4],0.f); r.y=fmaxf(acc0[5],0.f); r.z=fmaxf(acc0[6],0.f); r.w=fmaxf(acc0[7],0.f);
    *(float4*)(h0+4) = r;
    r.x=fmaxf(acc1[0],0.f); r.y=fmaxf(acc1[1],0.f); r.z=fmaxf(acc1[2],0.f); r.w=fmaxf(acc1[3],0.f);
    *(float4*)h1p = r;
    r.x=fmaxf(acc1[4],0.f); r.y=fmaxf(acc1[5],0.f); r.z=fmaxf(acc1[6],0.f); r.w=fmaxf(acc1[7],0.f);
    *(float4*)(h1p+4) = r;
  }
  {  // fps layer2: reads F1 (F3 buf), writes F2
    const int o = tq >> 1, kh = tq & 1;
    float a = 0.f;
    for (int k = kh * 32; k < kh * 32 + 32; ++k)
      a = fmaf(SH[L_F3 + tg * 128 + k], g_W[W2O + k * 64 + o], a);
    a += __shfl_xor(a, 1);
    if (kh == 0) SH[L_F2 + tg * 64 + o] = fmaxf(a + g_W[B2O + o], 0.f);
  }
  __syncthreads();

  // ===== Phase 3: 64->128 (acts h2 in AIN cols0-63), chunks [16][128] =====
  {
    const float4 b0 = *(const float4*)(g_W + B3O + o8);
    const float4 b1 = *(const float4*)(g_W + B3O + o8 + 4);
    const float4 b2 = *(const float4*)(g_W + B3O + 64 + o8);
    const float4 b3 = *(const float4*)(g_W + B3O + 64 + o8 + 4);
    acc0[0]=b0.x;  acc0[1]=b0.y;  acc0[2]=b0.z;  acc0[3]=b0.w;
    acc0[4]=b1.x;  acc0[5]=b1.y;  acc0[6]=b1.z;  acc0[7]=b1.w;
    acc0[8]=b2.x;  acc0[9]=b2.y;  acc0[10]=b2.z; acc0[11]=b2.w;
    acc0[12]=b3.x; acc0[13]=b3.y; acc0[14]=b3.z; acc0[15]=b3.w;
    #pragma unroll
    for (int j = 0; j < 16; ++j) acc1[j] = acc0[j];
  }
  #pragma unroll
  for (int cc = 0; cc < 4; ++cc) {
    float* wr = (cc & 1) ? wb0 : wb1;
    float* wn = (cc & 1) ? wb1 : wb0;
    if (cc < 3) stage_async(g_W + W3O + (cc + 1) * 2048, wn, 2048, t);
    else        stage_async(g_W + AO, wn, 1024, t);   // c9 = A0 k0-15
    const int kb = cc * 16;
    #pragma unroll 2
    for (int i4 = 0; i4 < 16; i4 += 4) {
      const float4 v0 = *(const float4*)(aA0 + kb + i4);
      const float4 v1 = *(const float4*)(aA1 + kb + i4);
      fma16x2(wr + (i4+0)*128 + o8, v0.x, v1.x, acc0, acc1);
      fma16x2(wr + (i4+1)*128 + o8, v0.y, v1.y, acc0, acc1);
      fma16x2(wr + (i4+2)*128 + o8, v0.z, v1.z, acc0, acc1);
      fma16x2(wr + (i4+3)*128 + o8, v0.w, v1.w, acc0, acc1);
    }
    if (cc == 3) {
      float* h0 = SH + L_H3 + s * 132 + o8;
      float* h1p = SH + L_H3 + 4224 + s * 132 + o8;
      float4 r;
      r.x=fmaxf(acc0[0],0.f); r.y=fmaxf(acc0[1],0.f); r.z=fmaxf(acc0[2],0.f); r.w=fmaxf(acc0[3],0.f);
      *(float4*)h0 = r;
      r.x=fmaxf(acc0[4],0.f); r.y=fmaxf(acc0[5],0.f); r.z=fmaxf(acc0[6],0.f); r.w=fmaxf(acc0[7],0.f);
      *(float4*)(h0+4) = r;
      r.x=fmaxf(acc0[8],0.f); r.y=fmaxf(acc0[9],0.f); r.z=fmaxf(acc0[10],0.f); r.w=fmaxf(acc0[11],0.f);
      *(float4*)(h0+64) = r;
      r.x=fmaxf(acc0[12],0.f); r.y=fmaxf(acc0[13],0.f); r.z=fmaxf(acc0[14],0.f); r.w=fmaxf(acc0[15],0.f);
      *(float4*)(h0+68) = r;
      r.x=fmaxf(acc1[0],0.f); r.y=fmaxf(acc1[1],0.f); r.z=fmaxf(acc1[2],0.f); r.w=fmaxf(acc1[3],0.f);
      *(float4*)h1p = r;
      r.x=fmaxf(acc1[4],0.f); r.y=fmaxf(acc1[5],0.f); r.z=fmaxf(acc1[6],0.f); r.w=fmaxf(acc1[7],0.f);
      *(float4*)(h1p+4) = r;
      r.x=fmaxf(acc1[8],0.f); r.y=fmaxf(acc1[9],0.f); r.z=fmaxf(acc1[10],0.f); r.w=fmaxf(acc1[11],0.f);
      *(float4*)(h1p+64) = r;
      r.x=fmaxf(acc1[12],0.f); r.y=fmaxf(acc1[13],0.f); r.z=fmaxf(acc1[14],0.f); r.w=fmaxf(acc1[15],0.f);
      *(float4*)(h1p+68) = r;
      // fps layer3: reads F2, writes F3 (full 128, over dead F1)
      const int o = tq;
      float a = 0.f;
      for (int k = 0; k < 64; ++k)
        a = fmaf(SH[L_F2 + tg * 64 + k], g_W[W3O + k * 128 + o], a);
      SH[L_F3 + tg * 128 + o] = fmaxf(a + g_W[B3O + o], 0.f);
    }
    __syncthreads();
  }

  // ===== ebias: EB[g][o] = [F3|new_xyz] . A_col(o); overwrites F3 =====
  {
    const int o = tq;
    const float* ap = g_W + AO + (o >> 6) * 8448 + (o & 63);
    float a = 0.f;
    for (int k = 0; k < 128; ++k)
      a = fmaf(SH[L_F3 + tg * 128 + k], ap[k * 64], a);
    #pragma unroll
    for (int d = 0; d < 3; ++d)
      a = fmaf(SH[L_AIN + tg * 2176 + d * 68 + 67], ap[(128 + d) * 64], a);
    __syncthreads();
    SH[L_F3 + tg * 128 + o] = a;   // EB
    __syncthreads();
  }

  // ===== Phase 5 + softmax, two column halves. Chunks [16][64] of A-half =====
  #pragma unroll
  for (int half = 0; half < 2; ++half) {
    #pragma unroll
    for (int j = 0; j < 8; ++j) acc0[j] = 0.f;
    #pragma unroll
    for (int j = 0; j < 8; ++j) acc1[j] = 0.f;
    // 9 chunk-steps: c(9..17) for half0 (parity: j even->wb1), c(18..26) half1 (j even->wb0)
    #pragma unroll
    for (int j = 0; j < 9; ++j) {
      float* wr, *wn;
      if (half == 0) { wr = (j & 1) ? wb0 : wb1; wn = (j & 1) ? wb1 : wb0; }
      else           { wr = (j & 1) ? wb1 : wb0; wn = (j & 1) ? wb0 : wb1; }
      if (j < 8) {
        const int nk = (j + 1 < 8) ? 1024 : 256;
        stage_async(g_W + AO + half * 8448 + (j + 1) * 1024, wn, nk, t);
      } else if (half == 0) {
        stage_async(g_W + AO + 8448, wn, 1024, t);   // c18 = A1 k0-15
      }
      const int kb = j * 16;
      const int rows = (j < 8) ? 16 : 4;
      for (int i4 = 0; i4 < rows; i4 += 4) {
        const float4 v0 = *(const float4*)(aH0 + kb + i4);
        const float4 v1 = *(const float4*)(aH1 + kb + i4);
        fma8x2(wr + (i4+0)*64 + o8, v0.x, v1.x, acc0, acc1);
        fma8x2(wr + (i4+1)*64 + o8, v0.y, v1.y, acc0, acc1);
        fma8x2(wr + (i4+2)*64 + o8, v0.z, v1.z, acc0, acc1);
        fma8x2(wr + (i4+3)*64 + o8, v0.w, v1.w, acc0, acc1);
      }
      __syncthreads();
    }
    // E = leaky(EB - acc) -> AIN alias (stride 68, cols 0..63)
    {
      const float* eb0 = SH + L_F3 + half * 64 + o8;
      const float* eb1 = SH + L_F3 + 128 + half * 64 + o8;
      float* e0 = SH + L_AIN + s * 68 + o8;
      float* e1 = SH + L_AIN + 2176 + s * 68 + o8;
      float4 r; float e;
      e=eb0[0]-acc0[0]; r.x=(e>0.f)?e:ALPHAn*e;
      e=eb0[1]-acc0[1]; r.y=(e>0.f)?e:ALPHAn*e;
      e=eb0[2]-acc0[2]; r.z=(e>0.f)?e:ALPHAn*e;
      e=eb0[3]-acc0[3]; r.w=(e>0.f)?e:ALPHAn*e;
      *(float4*)e0 = r;
      e=eb0[4]-acc0[4]; r.x=(e>0.f)?e:ALPHAn*e;
      e=eb0[5]-acc0[5]; r.y=(e>0.f)?e:ALPHAn*e;
      e=eb0[6]-acc0[6]; r.z=(e>0.f)?e:ALPHAn*e;
      e=eb0[7]-acc0[7]; r.w=(e>0.f)?e:ALPHAn*e;
      *(float4*)(e0+4) = r;
      e=eb1[0]-acc1[0]; r.x=(e>0.f)?e:ALPHAn*e;
      e=eb1[1]-acc1[1]; r.y=(e>0.f)?e:ALPHAn*e;
      e=eb1[2]-acc1[2]; r.z=(e>0.f)?e:ALPHAn*e;
      e=eb1[3]-acc1[3]; r.w=(e>0.f)?e:ALPHAn*e;
      *(float4*)e1 = r;
      e=eb1[4]-acc1[4]; r.x=(e>0.f)?e:ALPHAn*e;
      e=eb1[5]-acc1[5]; r.y=(e>0.f)?e:ALPHAn*e;
      e=eb1[6]-acc1[6]; r.z=(e>0.f)?e:ALPHAn*e;
      e=eb1[7]-acc1[7]; r.w=(e>0.f)?e:ALPHAn*e;
      *(float4*)(e1+4) = r;
    }
    __syncthreads();
    // softmax over s for this half's 64 cols x 2 groups (threads 0..127)
    if (t < 128) {
      const int g2 = t >> 6, c = t & 63;
      const float* ecol = SH + L_AIN + g2 * 2176 + c;
      const float* hcol = SH + L_H3 + g2 * 4224 + half * 64 + c;
      float mx = -3.4e38f;
      #pragma unroll 4
      for (int si = 0; si < 32; ++si) mx = fmaxf(mx, ecol[si * 68]);
      float den = 0.f, pool = 0.f;
      #pragma unroll 4
      for (int si = 0; si < 32; ++si) {
        const float w = __expf(ecol[si * 68] - mx);
        den += w;
        pool = fmaf(w, hcol[si * 132], pool);
      }
      const int gg2 = blockIdx.x * 2 + g2;
      out[Bn * 3 * Pn + (((gg2 >> 10) * 128) + half * 64 + c) * Pn + (gg2 & 1023)]
          = pool / den;
    }
    __syncthreads();   // E reused by next half
  }
}

extern "C" void kernel_launch(void* const* d_in, const int* in_sizes, int n_in,
                              void* d_out, int out_size, void* d_ws, size_t ws_size,
                              hipStream_t stream) {
  const float* xyz       = (const float*)d_in[0];
  const float* points    = (const float*)d_in[1];
  const int*   fps_idx   = (const int*)d_in[2];
  const int*   group_idx = (const int*)d_in[3];

  prep_kernel<<<(WSF + 255) / 256, 256, 0, stream>>>(
      (const float*)d_in[4],  (const float*)d_in[5],
      (const float*)d_in[6],  (const float*)d_in[7],
      (const float*)d_in[8],  (const float*)d_in[9],
      (const float*)d_in[10], (const float*)d_in[11],
      (const float*)d_in[12], (const float*)d_in[13],
      (const float*)d_in[14], (const float*)d_in[15],
      (const float*)d_in[16], (const float*)d_in[17],
      (const float*)d_in[18], (const float*)d_in[19],
      (const float*)d_in[20], (const float*)d_in[21],
      (const float*)d_in[22]);

  fused_kernel<<<Bn * Pn / 2, 256, 0, stream>>>(xyz, points, fps_idx, group_idx,
                                                (float*)d_out);
}